// Round 3
// baseline (2204.300 us; speedup 1.0000x reference)
//
#include <hip/hip_runtime.h>

// ---------------- problem constants ----------------
#define B_ 4
#define N_ 96
#define C_ 256
#define NPAIR (B_*N_*N_)        // 36864 pair rows
#define CE (NPAIR*C_)           // 9437184 elements in x
#define CE4 (CE/4)
#define SCALE 8.838834764831844f  // 50/sqrt(32)
#define BH_CHUNK 16             // heads (b*h) per attention chunk; 32 total -> 2 chunks

typedef __attribute__((ext_vector_type(4))) float f32x4;
typedef __attribute__((ext_vector_type(8))) __bf16 bf16x8;
typedef __attribute__((ext_vector_type(4))) unsigned short u16x4;

__device__ __forceinline__ unsigned short f2bf(float f){
  __bf16 h = (__bf16)f;                      // RNE convert
  return __builtin_bit_cast(unsigned short, h);
}

// async global->LDS, 16B per lane; lds dest = wave-uniform base + lane*16
__device__ __forceinline__ void gload16(const void* g, void* l){
  __builtin_amdgcn_global_load_lds((const __attribute__((address_space(1))) unsigned int*)g,
                                   (__attribute__((address_space(3))) unsigned int*)l,
                                   16, 0, 0);
}

// ---------------- K0: x = emb[adj] (fp32 copy) ----------------
__global__ __launch_bounds__(256) void k_gather(const int* __restrict__ adj,
                                                const float* __restrict__ emb,
                                                float* __restrict__ x){
  int pair = blockIdx.x; int c = threadIdx.x;
  int row = adj[pair];
  x[(size_t)pair*C_ + c] = emb[row*C_ + c];
}

// ---------------- K0b: qkv weights fp32 -> bf16 (all 4 layers) ----------------
__global__ __launch_bounds__(256) void k_wconv(const float* __restrict__ w,
                                               unsigned short* __restrict__ wb){
  int i = blockIdx.x*256 + threadIdx.x;      // 1280 blocks x 256 thr x 4 elem = 1,310,720
  f32x4 v = ((const f32x4*)w)[i];
  u16x4 o;
  o.x = f2bf(v.x); o.y = f2bf(v.y); o.z = f2bf(v.z); o.w = f2bf(v.w);
  ((u16x4*)wb)[i] = o;
}

// ---------------- K1: per-block sum/sumsq partials ----------------
__global__ __launch_bounds__(256) void k_stats1(const float* __restrict__ x, float2* __restrict__ part){
  int tid = threadIdx.x;
  int gid = blockIdx.x*256 + tid;           // 1024 blocks -> 262144 threads
  float s = 0.f, q = 0.f;
  const f32x4* x4 = (const f32x4*)x;
  for (int i = gid; i < CE4; i += 262144){  // exactly 9 iters for all threads
    f32x4 v = x4[i];
    s += v.x + v.y + v.z + v.w;
    q += v.x*v.x + v.y*v.y + v.z*v.z + v.w*v.w;
  }
  __shared__ float rs[256], rq[256];
  rs[tid] = s; rq[tid] = q; __syncthreads();
  for (int o = 128; o > 0; o >>= 1){
    if (tid < o){ rs[tid] += rs[tid+o]; rq[tid] += rq[tid+o]; }
    __syncthreads();
  }
  if (tid == 0){ float2 p; p.x = rs[0]; p.y = rq[0]; part[blockIdx.x] = p; }
}

// ---------------- K2: finalize mean / rstd (ddof=1) ----------------
__global__ __launch_bounds__(256) void k_stats2(const float2* __restrict__ part, float* __restrict__ stats){
  int tid = threadIdx.x;
  double s = 0.0, q = 0.0;
  for (int i = tid; i < 1024; i += 256){ float2 p = part[i]; s += (double)p.x; q += (double)p.y; }
  __shared__ double ds[256], dq[256];
  ds[tid] = s; dq[tid] = q; __syncthreads();
  for (int o = 128; o > 0; o >>= 1){
    if (tid < o){ ds[tid] += ds[tid+o]; dq[tid] += dq[tid+o]; }
    __syncthreads();
  }
  if (tid == 0){
    double S = ds[0], Q = dq[0];
    double mean = S / (double)CE;
    double var  = (Q - S*S/(double)CE) / (double)(CE - 1);
    stats[0] = (float)mean;
    stats[1] = (float)(1.0 / sqrt(var));
  }
}

// ---------------- K3: y = bf16((x-mean)*rstd) ----------------
__global__ __launch_bounds__(256) void k_norm(const float* __restrict__ x, const float* __restrict__ stats,
                                              unsigned short* __restrict__ y){
  float mean = stats[0], rstd = stats[1];
  int i = blockIdx.x*256 + threadIdx.x;    // 9216 blocks, one f32x4 each
  f32x4 v = ((const f32x4*)x)[i];
  u16x4 o;
  o.x = f2bf((v.x-mean)*rstd); o.y = f2bf((v.y-mean)*rstd);
  o.z = f2bf((v.z-mean)*rstd); o.w = f2bf((v.w-mean)*rstd);
  ((u16x4*)y)[i] = o;
}

// ---------------- K4: qkv GEMM, scatter epilogue ----------------
// C[m,n] = sum_k Y[m,k]*W[n,k];  M=36864 N=1280 K=256. 128x128 tile, BK=64.
__global__ __launch_bounds__(256) void k_gemm(const unsigned short* __restrict__ Y,
                                              const unsigned short* __restrict__ W,
                                              unsigned short* __restrict__ qn,
                                              unsigned short* __restrict__ qT,
                                              unsigned short* __restrict__ k1,
                                              unsigned short* __restrict__ k2T,
                                              unsigned short* __restrict__ v1,
                                              unsigned short* __restrict__ v2T){
  __shared__ unsigned short As[128*64];
  __shared__ unsigned short Bs[128*64];
  const int tid = threadIdx.x;
  const int w = tid >> 6, lane = tid & 63;
  const int quad = lane >> 4, l16 = lane & 15;
  const int m0 = blockIdx.y * 128, n0 = blockIdx.x * 128;
  const int mw = (w & 1) * 64, nw = (w >> 1) * 64;
  f32x4 acc[4][4] = {};

  for (int kt = 0; kt < 256; kt += 64){
    // stage A,B tiles: LDS slot s of row r holds global 16B chunk s^(r&7)
    const int rbase = w * 32;
    const int rowoff = lane >> 3;           // 0..7 (== row&7)
    const int kgx = lane & 7;               // lds chunk slot
    const int kg = kgx ^ rowoff;            // global chunk
    for (int i8 = 0; i8 < 4; ++i8){
      int row = rbase + i8*8 + rowoff;
      gload16(Y + (size_t)(m0+row)*256 + kt + kg*8, &As[(rbase + i8*8)*64]);
      gload16(W + (size_t)(n0+row)*256 + kt + kg*8, &Bs[(rbase + i8*8)*64]);
    }
    __syncthreads();
    for (int ks = 0; ks < 2; ++ks){
      bf16x8 af[4], bf[4];
      for (int t4 = 0; t4 < 4; ++t4){
        int rm = mw + t4*16 + l16;
        af[t4] = *(const bf16x8*)((const char*)As + rm*128 + ((((ks<<2)|quad) ^ (rm&7))*16));
        int rn = nw + t4*16 + l16;
        bf[t4] = *(const bf16x8*)((const char*)Bs + rn*128 + ((((ks<<2)|quad) ^ (rn&7))*16));
      }
      for (int mi = 0; mi < 4; ++mi)
        for (int ni = 0; ni < 4; ++ni)
          acc[mi][ni] = __builtin_amdgcn_mfma_f32_16x16x32_bf16(af[mi], bf[ni], acc[mi][ni], 0, 0, 0);
    }
    __syncthreads();
  }

  // epilogue: scatter to head-split tensors
  for (int mi = 0; mi < 4; ++mi){
    for (int ni = 0; ni < 4; ++ni){
      int gn = n0 + nw + ni*16 + l16;
      int t = gn >> 8, h = (gn >> 5) & 7, dd = gn & 31;
      for (int r = 0; r < 4; ++r){
        int gm = m0 + mw + mi*16 + quad*4 + r;
        int b = gm / 9216, rem = gm - b*9216;
        int ii = rem / 96, jj = rem - (rem/96)*96;
        unsigned short v = f2bf(acc[mi][ni][r]);
        size_t nat = (((size_t)(b*8+h)*96 + ii)*96 + jj)*32 + dd;
        size_t tra = (((size_t)(b*8+h)*96 + jj)*96 + ii)*32 + dd;
        switch (t){
          case 0: qn[nat] = v; qT[tra] = v; break;
          case 1: k1[nat] = v; break;
          case 2: k2T[tra] = v; break;
          case 3: v1[nat] = v; break;
          case 4: v2T[tra] = v; break;
        }
      }
    }
  }
}

// ---------------- K5: branch-1 scores (chunked over bh) ----------------
// block = bh_local*96 + i; s1[bh_local,i,j,p] = scale * (q[i,j,:] . k1[i,p,:])  (fp16)
__global__ __launch_bounds__(256) void k_scores1(const unsigned short* __restrict__ qn,
                                                 const unsigned short* __restrict__ k1,
                                                 _Float16* __restrict__ s1,
                                                 int bh0){
  __shared__ unsigned short Qs[96*40], Ks[96*40];
  int wg = blockIdx.x;                       // bh_local*96 + i
  int tid = threadIdx.x;
  size_t gslab = ((size_t)bh0*96 + wg)*3072;
  const unsigned short* qp = qn + gslab;
  const unsigned short* kp = k1 + gslab;
  for (int g = tid; g < 768; g += 256){
    int j = g >> 3, q4 = g & 7;
    *(u16x4*)&Qs[j*40 + q4*4] = *(const u16x4*)&qp[j*32 + q4*4];
    *(u16x4*)&Ks[j*40 + q4*4] = *(const u16x4*)&kp[j*32 + q4*4];
  }
  __syncthreads();
  int w = tid >> 6, lane = tid & 63, quad = lane >> 4, l16 = lane & 15;
  _Float16* sp = s1 + (size_t)wg*9216;
  for (int r = 0; r < 9; ++r){
    int tile = w*9 + r; int jt = tile/6, pt = tile - jt*6;
    bf16x8 a = *(const bf16x8*)((const char*)Qs + (jt*16 + l16)*80 + quad*16);
    bf16x8 b = *(const bf16x8*)((const char*)Ks + (pt*16 + l16)*80 + quad*16);
    f32x4 c = {0.f,0.f,0.f,0.f};
    c = __builtin_amdgcn_mfma_f32_16x16x32_bf16(a, b, c, 0, 0, 0);
    int col = pt*16 + l16;
    for (int rr = 0; rr < 4; ++rr){
      int row = jt*16 + quad*4 + rr;
      sp[row*96 + col] = (_Float16)(c[rr] * SCALE);
    }
  }
}

// ---------------- K6: branch-2 scores + softmax + O2, per (bh_local, j) ----------------
__global__ __launch_bounds__(256) void k_attn2(const unsigned short* __restrict__ qT,
                                               const unsigned short* __restrict__ k2T,
                                               const unsigned short* __restrict__ v2T,
                                               const _Float16* __restrict__ s1,
                                               unsigned short* __restrict__ a_out,
                                               float* __restrict__ x,
                                               int bh0){
  __shared__ unsigned short Qs[96*40], Ks[96*40], Vd[32*112];
  __shared__ float Sf[96*100];
  int wg = blockIdx.x; int bhl = wg/96, jj = wg - bhl*96;
  int bh = bh0 + bhl;
  int b = bh >> 3, h = bh & 7;
  int tid = threadIdx.x;
  size_t gslab = ((size_t)bh*96 + jj)*3072;
  const unsigned short* qp = qT  + gslab;
  const unsigned short* kp = k2T + gslab;
  const unsigned short* vp = v2T + gslab;
  for (int g = tid; g < 768; g += 256){
    int p = g >> 3, q4 = g & 7;
    *(u16x4*)&Qs[p*40 + q4*4] = *(const u16x4*)&qp[p*32 + q4*4];
    *(u16x4*)&Ks[p*40 + q4*4] = *(const u16x4*)&kp[p*32 + q4*4];
    u16x4 v = *(const u16x4*)&vp[p*32 + q4*4];
    int d0 = q4*4;
    Vd[(d0+0)*112 + p] = v.x; Vd[(d0+1)*112 + p] = v.y;
    Vd[(d0+2)*112 + p] = v.z; Vd[(d0+3)*112 + p] = v.w;
  }
  __syncthreads();
  int w = tid >> 6, lane = tid & 63, quad = lane >> 4, l16 = lane & 15;
  // S2 tiles + add s1
  for (int r = 0; r < 9; ++r){
    int tile = w*9 + r; int it = tile/6, pt = tile - it*6;
    bf16x8 a = *(const bf16x8*)((const char*)Qs + (it*16 + l16)*80 + quad*16);
    bf16x8 bb = *(const bf16x8*)((const char*)Ks + (pt*16 + l16)*80 + quad*16);
    f32x4 c = {0.f,0.f,0.f,0.f};
    c = __builtin_amdgcn_mfma_f32_16x16x32_bf16(a, bb, c, 0, 0, 0);
    int col = pt*16 + l16;
    for (int rr = 0; rr < 4; ++rr){
      int row = it*16 + quad*4 + rr;   // i
      float v = c[rr]*SCALE + (float)s1[(((size_t)bhl*96 + row)*96 + jj)*96 + col];
      Sf[row*100 + col] = v;
    }
  }
  __syncthreads();
  // softmax over p per row i
  if (tid < 96){
    float* rowp = &Sf[tid*100];
    float m = -1e30f;
    for (int p = 0; p < 96; ++p) m = fmaxf(m, rowp[p]);
    float s = 0.f;
    for (int p = 0; p < 96; ++p){ float e = __expf(rowp[p] - m); rowp[p] = e; s += e; }
    float inv = 1.f / s;
    for (int p = 0; p < 96; ++p) rowp[p] *= inv;
  }
  __syncthreads();
  // write probs (layout [bh_local, j, i, p])
  unsigned short* ap = a_out + (size_t)wg*9216;
  for (int g = tid; g < 9216; g += 256){
    int i = g / 96, p = g - i*96;
    ap[g] = f2bf(Sf[i*100 + p]);
  }
  // O2 = A(96i x 96p) @ V2(96p x 32d) -> store x[b,i,jj,h*32+d]
  for (int r = 0; r < 3; ++r){
    int tile = w*3 + r; int it = tile >> 1, dt = tile & 1;
    f32x4 c = {0.f,0.f,0.f,0.f};
    for (int kp3 = 0; kp3 < 3; ++kp3){
      int row = it*16 + l16;
      const float* sp = &Sf[row*100 + kp3*32 + quad*8];
      bf16x8 a;
      for (int t = 0; t < 8; ++t) a[t] = (__bf16)sp[t];
      bf16x8 bb = *(const bf16x8*)((const char*)Vd + (dt*16 + l16)*224 + kp3*64 + quad*16);
      c = __builtin_amdgcn_mfma_f32_16x16x32_bf16(a, bb, c, 0, 0, 0);
    }
    int d = dt*16 + l16;
    for (int rr = 0; rr < 4; ++rr){
      int i = it*16 + quad*4 + rr;
      x[(((size_t)b*96 + i)*96 + jj)*256 + h*32 + d] = c[rr];
    }
  }
}

// ---------------- K7: O1 per (bh_local, i), x += A @ V1 ----------------
__global__ __launch_bounds__(256) void k_attn1(const unsigned short* __restrict__ a_in,
                                               const unsigned short* __restrict__ v1,
                                               float* __restrict__ x,
                                               int bh0){
  __shared__ unsigned short As[96*112], Vd[32*112];
  int wg = blockIdx.x; int bhl = wg/96, ii = wg - bhl*96;
  int bh = bh0 + bhl;
  int b = bh >> 3, h = bh & 7;
  int tid = threadIdx.x;
  const unsigned short* vp = v1 + ((size_t)bh*96 + ii)*3072;
  for (int g = tid; g < 768; g += 256){
    int p = g >> 3, q4 = g & 7;
    u16x4 v = *(const u16x4*)&vp[p*32 + q4*4];
    int d0 = q4*4;
    Vd[(d0+0)*112 + p] = v.x; Vd[(d0+1)*112 + p] = v.y;
    Vd[(d0+2)*112 + p] = v.z; Vd[(d0+3)*112 + p] = v.w;
  }
  for (int g = tid; g < 2304; g += 256){
    int j = g / 24, q4 = g - j*24;
    *(u16x4*)&As[j*112 + q4*4] =
      *(const u16x4*)&a_in[((size_t)(bhl*96 + j))*9216 + ii*96 + q4*4];
  }
  __syncthreads();
  int w = tid >> 6, lane = tid & 63, quad = lane >> 4, l16 = lane & 15;
  for (int r = 0; r < 3; ++r){
    int tile = w*3 + r; int jt = tile >> 1, dt = tile & 1;
    f32x4 c = {0.f,0.f,0.f,0.f};
    for (int kp3 = 0; kp3 < 3; ++kp3){
      bf16x8 a = *(const bf16x8*)((const char*)As + (jt*16 + l16)*224 + kp3*64 + quad*16);
      bf16x8 bb = *(const bf16x8*)((const char*)Vd + (dt*16 + l16)*224 + kp3*64 + quad*16);
      c = __builtin_amdgcn_mfma_f32_16x16x32_bf16(a, bb, c, 0, 0, 0);
    }
    int d = dt*16 + l16;
    for (int rr = 0; rr < 4; ++rr){
      int j = jt*16 + quad*4 + rr;
      size_t xi = (((size_t)b*96 + ii)*96 + j)*256 + h*32 + d;
      x[xi] += c[rr];
    }
  }
}

// ---------------- K8: pool partials over (i,j) ----------------
__global__ __launch_bounds__(256) void k_pool(const float* __restrict__ x, float* __restrict__ part){
  int b = blockIdx.x >> 5, ch = blockIdx.x & 31, t = threadIdx.x;
  const float* xp = x + ((size_t)b*9216 + ch*288)*256 + t;
  float s = 0.f;
  for (int r = 0; r < 288; ++r) s += xp[(size_t)r*256];
  part[(size_t)blockIdx.x*256 + t] = s;
}

// ---------------- K9: head (fp32 weights, fp32 out) ----------------
__global__ __launch_bounds__(256) void k_head(const float* __restrict__ part,
                                              const float* __restrict__ hw,
                                              const float* __restrict__ hb,
                                              float* __restrict__ out){
  int b = blockIdx.x, t = threadIdx.x;
  float s = 0.f;
  for (int k = 0; k < 32; ++k) s += part[(size_t)(b*32 + k)*256 + t];
  __shared__ float xm[256];
  xm[t] = s * (1.0f/9216.0f);
  __syncthreads();
  float o = hb[t];
  for (int c = 0; c < 256; ++c) o += xm[c] * hw[t*256 + c];
  out[b*256 + t] = o;
}

// ---------------- launch ----------------
extern "C" void kernel_launch(void* const* d_in, const int* in_sizes, int n_in,
                              void* d_out, int out_size, void* d_ws, size_t ws_size,
                              hipStream_t stream){
  (void)in_sizes; (void)n_in; (void)out_size; (void)ws_size;
  const int*   adj  = (const int*)d_in[0];
  const float* emb  = (const float*)d_in[1];
  const float* qkvw = (const float*)d_in[2];
  const float* hw   = (const float*)d_in[3];
  const float* hb   = (const float*)d_in[4];

  // workspace layout (~210.4 MB total)
  char* p = (char*)d_ws;
  float*          x    = (float*)p;          p += (size_t)CE*4;            //  37.75 MB
  unsigned short* qn   = (unsigned short*)p; p += (size_t)CE*2;            // 6 x 18.87 MB
  unsigned short* qT   = (unsigned short*)p; p += (size_t)CE*2;
  unsigned short* k1   = (unsigned short*)p; p += (size_t)CE*2;
  unsigned short* k2T  = (unsigned short*)p; p += (size_t)CE*2;
  unsigned short* v1   = (unsigned short*)p; p += (size_t)CE*2;
  unsigned short* v2T  = (unsigned short*)p; p += (size_t)CE*2;
  // region R1: y (bf16, 18.87 MB) aliased under s1 chunk (fp16, 28.31 MB)
  unsigned short* y    = (unsigned short*)p;
  _Float16*       s1   = (_Float16*)p;       p += (size_t)BH_CHUNK*96*9216*2;
  unsigned short* aP   = (unsigned short*)p; p += (size_t)BH_CHUNK*96*9216*2; // 28.31 MB
  unsigned short* wbf  = (unsigned short*)p; p += (size_t)4*1280*256*2;       //  2.62 MB
  float2*         part = (float2*)p;         p += 1024*8;
  float*          stats= (float*)p;          p += 256;
  float*          pool = (float*)p;          p += 128*256*4;

  k_gather<<<dim3(NPAIR), dim3(256), 0, stream>>>(adj, emb, x);
  k_wconv <<<dim3(1280),  dim3(256), 0, stream>>>(qkvw, wbf);
  for (int l = 0; l < 4; ++l){
    k_stats1<<<dim3(1024), dim3(256), 0, stream>>>(x, part);
    k_stats2<<<dim3(1),    dim3(256), 0, stream>>>(part, stats);
    k_norm  <<<dim3(9216), dim3(256), 0, stream>>>(x, stats, y);
    k_gemm  <<<dim3(10, 288), dim3(256), 0, stream>>>(y, wbf + (size_t)l*1280*256,
                                                      qn, qT, k1, k2T, v1, v2T);
    for (int c0 = 0; c0 < 32; c0 += BH_CHUNK){
      k_scores1<<<dim3(BH_CHUNK*96), dim3(256), 0, stream>>>(qn, k1, s1, c0);
      k_attn2 <<<dim3(BH_CHUNK*96), dim3(256), 0, stream>>>(qT, k2T, v2T, s1, aP, x, c0);
      k_attn1 <<<dim3(BH_CHUNK*96), dim3(256), 0, stream>>>(aP, v1, x, c0);
    }
  }
  k_pool<<<dim3(128), dim3(256), 0, stream>>>(x, pool);
  k_head<<<dim3(4),   dim3(256), 0, stream>>>(pool, hw, hb, (float*)d_out);
}

// Round 4
// 885.932 us; speedup vs baseline: 2.4881x; 2.4881x over previous
//
#include <hip/hip_runtime.h>

// ---------------- problem constants ----------------
#define B_ 4
#define N_ 96
#define C_ 256
#define NPAIR (B_*N_*N_)        // 36864 pair rows
#define CE (NPAIR*C_)           // 9437184 elements per qkv slab
#define CE4 (CE/4)
#define SCALE 8.838834764831844f  // 50/sqrt(32)
#define BH_CHUNK 16             // heads (b*h) per attention chunk; 32 total -> 2 chunks

typedef __attribute__((ext_vector_type(4))) float f32x4;
typedef __attribute__((ext_vector_type(8))) __bf16 bf16x8;
typedef __attribute__((ext_vector_type(4))) unsigned short u16x4;
typedef __attribute__((ext_vector_type(8))) unsigned short u16x8;

__device__ __forceinline__ unsigned short f2bf(float f){
  __bf16 h = (__bf16)f;                      // RNE convert
  return __builtin_bit_cast(unsigned short, h);
}

// async global->LDS, 16B per lane; lds dest = wave-uniform base + lane*16
__device__ __forceinline__ void gload16(const void* g, void* l){
  __builtin_amdgcn_global_load_lds((const __attribute__((address_space(1))) unsigned int*)g,
                                   (__attribute__((address_space(3))) unsigned int*)l,
                                   16, 0, 0);
}

// ---------------- K0: x = emb[adj] (fp32 copy) ----------------
__global__ __launch_bounds__(256) void k_gather(const int* __restrict__ adj,
                                                const float* __restrict__ emb,
                                                float* __restrict__ x){
  int pair = blockIdx.x; int c = threadIdx.x;
  int row = adj[pair];
  x[(size_t)pair*C_ + c] = emb[row*C_ + c];
}

// ---------------- K0b: qkv weights fp32 -> bf16 (all 4 layers) ----------------
__global__ __launch_bounds__(256) void k_wconv(const float* __restrict__ w,
                                               unsigned short* __restrict__ wb){
  int i = blockIdx.x*256 + threadIdx.x;      // 1280 blocks x 256 thr x 4 elem
  f32x4 v = ((const f32x4*)w)[i];
  u16x4 o;
  o.x = f2bf(v.x); o.y = f2bf(v.y); o.z = f2bf(v.z); o.w = f2bf(v.w);
  ((u16x4*)wb)[i] = o;
}

// ---------------- K1: per-block sum/sumsq partials ----------------
__global__ __launch_bounds__(256) void k_stats1(const float* __restrict__ x, float2* __restrict__ part){
  int tid = threadIdx.x;
  int gid = blockIdx.x*256 + tid;           // 1024 blocks -> 262144 threads
  float s = 0.f, q = 0.f;
  const f32x4* x4 = (const f32x4*)x;
  for (int i = gid; i < CE4; i += 262144){  // exactly 9 iters for all threads
    f32x4 v = x4[i];
    s += v.x + v.y + v.z + v.w;
    q += v.x*v.x + v.y*v.y + v.z*v.z + v.w*v.w;
  }
  __shared__ float rs[256], rq[256];
  rs[tid] = s; rq[tid] = q; __syncthreads();
  for (int o = 128; o > 0; o >>= 1){
    if (tid < o){ rs[tid] += rs[tid+o]; rq[tid] += rq[tid+o]; }
    __syncthreads();
  }
  if (tid == 0){ float2 p; p.x = rs[0]; p.y = rq[0]; part[blockIdx.x] = p; }
}

// ---------------- K2: finalize mean / rstd (ddof=1) ----------------
__global__ __launch_bounds__(256) void k_stats2(const float2* __restrict__ part, float* __restrict__ stats){
  int tid = threadIdx.x;
  double s = 0.0, q = 0.0;
  for (int i = tid; i < 1024; i += 256){ float2 p = part[i]; s += (double)p.x; q += (double)p.y; }
  __shared__ double ds[256], dq[256];
  ds[tid] = s; dq[tid] = q; __syncthreads();
  for (int o = 128; o > 0; o >>= 1){
    if (tid < o){ ds[tid] += ds[tid+o]; dq[tid] += dq[tid+o]; }
    __syncthreads();
  }
  if (tid == 0){
    double S = ds[0], Q = dq[0];
    double mean = S / (double)CE;
    double var  = (Q - S*S/(double)CE) / (double)(CE - 1);
    stats[0] = (float)mean;
    stats[1] = (float)(1.0 / sqrt(var));
  }
}

// ---------------- K3: y = bf16((x-mean)*rstd) ----------------
__global__ __launch_bounds__(256) void k_norm(const float* __restrict__ x, const float* __restrict__ stats,
                                              unsigned short* __restrict__ y){
  float mean = stats[0], rstd = stats[1];
  int i = blockIdx.x*256 + threadIdx.x;    // 9216 blocks, one f32x4 each
  f32x4 v = ((const f32x4*)x)[i];
  u16x4 o;
  o.x = f2bf((v.x-mean)*rstd); o.y = f2bf((v.y-mean)*rstd);
  o.z = f2bf((v.z-mean)*rstd); o.w = f2bf((v.w-mean)*rstd);
  ((u16x4*)y)[i] = o;
}

// ---------------- K4: qkv GEMM, LDS-staged coalesced epilogue ----------------
// C[m,n] = sum_k Y[m,k]*W[n,k];  M=36864 N=1280 K=256. 128x128 tile, BK=64.
// Output: qkv5[slab][bh][i][j][d], slab in {q,k1,k2,v1,v2}, all natural layout.
__global__ __launch_bounds__(256) void k_gemm(const unsigned short* __restrict__ Y,
                                              const unsigned short* __restrict__ W,
                                              unsigned short* __restrict__ qkv5){
  __shared__ unsigned short smem[128*128];   // 32 KB: As | Bs during K-loop, C-stage in epilogue
  unsigned short* As = smem;
  unsigned short* Bs = smem + 128*64;
  const int tid = threadIdx.x;
  const int w = tid >> 6, lane = tid & 63;
  const int quad = lane >> 4, l16 = lane & 15;
  const int m0 = blockIdx.y * 128, n0 = blockIdx.x * 128;
  const int mw = (w & 1) * 64, nw = (w >> 1) * 64;
  f32x4 acc[4][4] = {};

  for (int kt = 0; kt < 256; kt += 64){
    // stage A,B tiles: LDS slot s of row r holds global 16B chunk s^(r&7)
    const int rbase = w * 32;
    const int rowoff = lane >> 3;           // 0..7 (== row&7)
    const int kgx = lane & 7;               // lds chunk slot
    const int kg = kgx ^ rowoff;            // global chunk
    for (int i8 = 0; i8 < 4; ++i8){
      int row = rbase + i8*8 + rowoff;
      gload16(Y + (size_t)(m0+row)*256 + kt + kg*8, &As[(rbase + i8*8)*64]);
      gload16(W + (size_t)(n0+row)*256 + kt + kg*8, &Bs[(rbase + i8*8)*64]);
    }
    __syncthreads();
    for (int ks = 0; ks < 2; ++ks){
      bf16x8 af[4], bf[4];
      for (int t4 = 0; t4 < 4; ++t4){
        int rm = mw + t4*16 + l16;
        af[t4] = *(const bf16x8*)((const char*)As + rm*128 + ((((ks<<2)|quad) ^ (rm&7))*16));
        int rn = nw + t4*16 + l16;
        bf[t4] = *(const bf16x8*)((const char*)Bs + rn*128 + ((((ks<<2)|quad) ^ (rn&7))*16));
      }
      for (int mi = 0; mi < 4; ++mi)
        for (int ni = 0; ni < 4; ++ni)
          acc[mi][ni] = __builtin_amdgcn_mfma_f32_16x16x32_bf16(af[mi], bf[ni], acc[mi][ni], 0, 0, 0);
    }
    __syncthreads();
  }

  // ---- epilogue: stage C tile (bf16) in LDS, then coalesced vector stores ----
  for (int mi = 0; mi < 4; ++mi)
    for (int ni = 0; ni < 4; ++ni)
      for (int r = 0; r < 4; ++r){
        int row = mw + mi*16 + quad*4 + r;
        int col = nw + ni*16 + l16;
        smem[row*128 + col] = f2bf(acc[mi][ni][r]);
      }
  __syncthreads();

  const int t_slab = n0 >> 8;               // n-tile lies fully within one slab
  const int hbase  = (n0 >> 5) & 7;
  unsigned short* slab = qkv5 + (size_t)t_slab*CE;
  const int trow = tid >> 4;                // 0..15
  const int tcol = (tid & 15) * 8;          // 0..120
  const int h  = hbase + (tcol >> 5);
  const int dd = tcol & 31;
  for (int pass = 0; pass < 8; ++pass){
    int row = pass*16 + trow;
    int gm = m0 + row;
    int b = gm / 9216; int rem = gm - b*9216;
    int ii = rem / 96, jj = rem - (rem/96)*96;
    u16x8 vv = *(const u16x8*)&smem[row*128 + tcol];
    *(u16x8*)&slab[(((size_t)(b*8+h)*96 + ii)*96 + jj)*32 + dd] = vv;
  }
}

// ---------------- K5: branch-1 scores (chunked over bh) ----------------
// block = bh_local*96 + i; s1[bh_local,i,j,p] = scale * (q[i,j,:] . k1[i,p,:])  (fp16)
__global__ __launch_bounds__(256) void k_scores1(const unsigned short* __restrict__ qkv5,
                                                 _Float16* __restrict__ s1,
                                                 int bh0){
  __shared__ unsigned short Qs[96*40], Ks[96*40];
  int wg = blockIdx.x;                       // bh_local*96 + i
  int tid = threadIdx.x;
  size_t gslab = ((size_t)bh0*96 + wg)*3072;
  const unsigned short* qp = qkv5 + 0*(size_t)CE + gslab;   // q  [bh][i][j][d]
  const unsigned short* kp = qkv5 + 1*(size_t)CE + gslab;   // k1 [bh][i][p][d]
  for (int g = tid; g < 768; g += 256){
    int j = g >> 3, q4 = g & 7;
    *(u16x4*)&Qs[j*40 + q4*4] = *(const u16x4*)&qp[j*32 + q4*4];
    *(u16x4*)&Ks[j*40 + q4*4] = *(const u16x4*)&kp[j*32 + q4*4];
  }
  __syncthreads();
  int w = tid >> 6, lane = tid & 63, quad = lane >> 4, l16 = lane & 15;
  _Float16* sp = s1 + (size_t)wg*9216;
  for (int r = 0; r < 9; ++r){
    int tile = w*9 + r; int jt = tile/6, pt = tile - jt*6;
    bf16x8 a = *(const bf16x8*)((const char*)Qs + (jt*16 + l16)*80 + quad*16);
    bf16x8 b = *(const bf16x8*)((const char*)Ks + (pt*16 + l16)*80 + quad*16);
    f32x4 c = {0.f,0.f,0.f,0.f};
    c = __builtin_amdgcn_mfma_f32_16x16x32_bf16(a, b, c, 0, 0, 0);
    int col = pt*16 + l16;
    for (int rr = 0; rr < 4; ++rr){
      int row = jt*16 + quad*4 + rr;
      sp[row*96 + col] = (_Float16)(c[rr] * SCALE);
    }
  }
}

// ---------------- K6: branch-2 scores + softmax + O2, per (bh_local, j) ----------------
// q, k2, v2 read strided from natural layout (transpose-on-the-fly in staging).
__global__ __launch_bounds__(256) void k_attn2(const unsigned short* __restrict__ qkv5,
                                               const _Float16* __restrict__ s1,
                                               unsigned short* __restrict__ a_out,
                                               float* __restrict__ x,
                                               int bh0){
  __shared__ unsigned short Qs[96*40], Ks[96*40], Vd[32*112];
  __shared__ float Sf[96*100];
  int wg = blockIdx.x; int bhl = wg/96, jj = wg - bhl*96;
  int bh = bh0 + bhl;
  int b = bh >> 3, h = bh & 7;
  int tid = threadIdx.x;
  const unsigned short* qn  = qkv5 + 0*(size_t)CE;
  const unsigned short* k2n = qkv5 + 2*(size_t)CE;
  const unsigned short* v2n = qkv5 + 4*(size_t)CE;
  for (int g = tid; g < 768; g += 256){
    int p = g >> 3, q4 = g & 7;                 // p = row index (i or pivot), q4*4 = d0
    size_t base = (((size_t)bh*96 + p)*96 + jj)*32 + q4*4;
    *(u16x4*)&Qs[p*40 + q4*4] = *(const u16x4*)&qn[base];
    *(u16x4*)&Ks[p*40 + q4*4] = *(const u16x4*)&k2n[base];
    u16x4 v = *(const u16x4*)&v2n[base];
    int d0 = q4*4;
    Vd[(d0+0)*112 + p] = v.x; Vd[(d0+1)*112 + p] = v.y;
    Vd[(d0+2)*112 + p] = v.z; Vd[(d0+3)*112 + p] = v.w;
  }
  __syncthreads();
  int w = tid >> 6, lane = tid & 63, quad = lane >> 4, l16 = lane & 15;
  // S2 tiles + add s1
  for (int r = 0; r < 9; ++r){
    int tile = w*9 + r; int it = tile/6, pt = tile - it*6;
    bf16x8 a = *(const bf16x8*)((const char*)Qs + (it*16 + l16)*80 + quad*16);
    bf16x8 bb = *(const bf16x8*)((const char*)Ks + (pt*16 + l16)*80 + quad*16);
    f32x4 c = {0.f,0.f,0.f,0.f};
    c = __builtin_amdgcn_mfma_f32_16x16x32_bf16(a, bb, c, 0, 0, 0);
    int col = pt*16 + l16;
    for (int rr = 0; rr < 4; ++rr){
      int row = it*16 + quad*4 + rr;   // i
      float v = c[rr]*SCALE + (float)s1[(((size_t)bhl*96 + row)*96 + jj)*96 + col];
      Sf[row*100 + col] = v;
    }
  }
  __syncthreads();
  // softmax over p per row i
  if (tid < 96){
    float* rowp = &Sf[tid*100];
    float m = -1e30f;
    for (int p = 0; p < 96; ++p) m = fmaxf(m, rowp[p]);
    float s = 0.f;
    for (int p = 0; p < 96; ++p){ float e = __expf(rowp[p] - m); rowp[p] = e; s += e; }
    float inv = 1.f / s;
    for (int p = 0; p < 96; ++p) rowp[p] *= inv;
  }
  __syncthreads();
  // write probs (layout [bh_local, j, i, p])
  unsigned short* ap = a_out + (size_t)wg*9216;
  for (int g = tid; g < 9216; g += 256){
    int i = g / 96, p = g - i*96;
    ap[g] = f2bf(Sf[i*100 + p]);
  }
  // O2 = A(96i x 96p) @ V2(96p x 32d) -> store x[b,i,jj,h*32+d]
  for (int r = 0; r < 3; ++r){
    int tile = w*3 + r; int it = tile >> 1, dt = tile & 1;
    f32x4 c = {0.f,0.f,0.f,0.f};
    for (int kp3 = 0; kp3 < 3; ++kp3){
      int row = it*16 + l16;
      const float* sp = &Sf[row*100 + kp3*32 + quad*8];
      bf16x8 a;
      for (int t = 0; t < 8; ++t) a[t] = (__bf16)sp[t];
      bf16x8 bb = *(const bf16x8*)((const char*)Vd + (dt*16 + l16)*224 + kp3*64 + quad*16);
      c = __builtin_amdgcn_mfma_f32_16x16x32_bf16(a, bb, c, 0, 0, 0);
    }
    int d = dt*16 + l16;
    for (int rr = 0; rr < 4; ++rr){
      int i = it*16 + quad*4 + rr;
      x[(((size_t)b*96 + i)*96 + jj)*256 + h*32 + d] = c[rr];
    }
  }
}

// ---------------- K7: O1 per (bh_local, i), x += A @ V1 ----------------
__global__ __launch_bounds__(256) void k_attn1(const unsigned short* __restrict__ a_in,
                                               const unsigned short* __restrict__ qkv5,
                                               float* __restrict__ x,
                                               int bh0){
  __shared__ unsigned short As[96*112], Vd[32*112];
  int wg = blockIdx.x; int bhl = wg/96, ii = wg - bhl*96;
  int bh = bh0 + bhl;
  int b = bh >> 3, h = bh & 7;
  int tid = threadIdx.x;
  const unsigned short* vp = qkv5 + 3*(size_t)CE + ((size_t)bh*96 + ii)*3072;  // v1 [bh][i][p][d]
  for (int g = tid; g < 768; g += 256){
    int p = g >> 3, q4 = g & 7;
    u16x4 v = *(const u16x4*)&vp[p*32 + q4*4];
    int d0 = q4*4;
    Vd[(d0+0)*112 + p] = v.x; Vd[(d0+1)*112 + p] = v.y;
    Vd[(d0+2)*112 + p] = v.z; Vd[(d0+3)*112 + p] = v.w;
  }
  for (int g = tid; g < 2304; g += 256){
    int j = g / 24, q4 = g - j*24;
    *(u16x4*)&As[j*112 + q4*4] =
      *(const u16x4*)&a_in[((size_t)(bhl*96 + j))*9216 + ii*96 + q4*4];
  }
  __syncthreads();
  int w = tid >> 6, lane = tid & 63, quad = lane >> 4, l16 = lane & 15;
  for (int r = 0; r < 3; ++r){
    int tile = w*3 + r; int jt = tile >> 1, dt = tile & 1;
    f32x4 c = {0.f,0.f,0.f,0.f};
    for (int kp3 = 0; kp3 < 3; ++kp3){
      bf16x8 a = *(const bf16x8*)((const char*)As + (jt*16 + l16)*224 + kp3*64 + quad*16);
      bf16x8 bb = *(const bf16x8*)((const char*)Vd + (dt*16 + l16)*224 + kp3*64 + quad*16);
      c = __builtin_amdgcn_mfma_f32_16x16x32_bf16(a, bb, c, 0, 0, 0);
    }
    int d = dt*16 + l16;
    for (int rr = 0; rr < 4; ++rr){
      int j = jt*16 + quad*4 + rr;
      size_t xi = (((size_t)b*96 + ii)*96 + j)*256 + h*32 + d;
      x[xi] += c[rr];
    }
  }
}

// ---------------- K8: pool partials over (i,j) ----------------
__global__ __launch_bounds__(256) void k_pool(const float* __restrict__ x, float* __restrict__ part){
  int b = blockIdx.x >> 5, ch = blockIdx.x & 31, t = threadIdx.x;
  const float* xp = x + ((size_t)b*9216 + ch*288)*256 + t;
  float s = 0.f;
  for (int r = 0; r < 288; ++r) s += xp[(size_t)r*256];
  part[(size_t)blockIdx.x*256 + t] = s;
}

// ---------------- K9: head (fp32 weights, fp32 out) ----------------
__global__ __launch_bounds__(256) void k_head(const float* __restrict__ part,
                                              const float* __restrict__ hw,
                                              const float* __restrict__ hb,
                                              float* __restrict__ out){
  int b = blockIdx.x, t = threadIdx.x;
  float s = 0.f;
  for (int k = 0; k < 32; ++k) s += part[(size_t)(b*32 + k)*256 + t];
  __shared__ float xm[256];
  xm[t] = s * (1.0f/9216.0f);
  __syncthreads();
  float o = hb[t];
  for (int c = 0; c < 256; ++c) o += xm[c] * hw[t*256 + c];
  out[b*256 + t] = o;
}

// ---------------- launch ----------------
extern "C" void kernel_launch(void* const* d_in, const int* in_sizes, int n_in,
                              void* d_out, int out_size, void* d_ws, size_t ws_size,
                              hipStream_t stream){
  (void)in_sizes; (void)n_in; (void)out_size; (void)ws_size;
  const int*   adj  = (const int*)d_in[0];
  const float* emb  = (const float*)d_in[1];
  const float* qkvw = (const float*)d_in[2];
  const float* hw   = (const float*)d_in[3];
  const float* hb   = (const float*)d_in[4];

  // workspace layout (~192 MB total)
  char* p = (char*)d_ws;
  float*          x    = (float*)p;          p += (size_t)CE*4;            //  37.75 MB
  unsigned short* qkv5 = (unsigned short*)p; p += (size_t)5*CE*2;          //  94.37 MB
  // region R1: y (bf16, 18.87 MB) aliased under s1 chunk (fp16, 28.31 MB)
  unsigned short* y    = (unsigned short*)p;
  _Float16*       s1   = (_Float16*)p;       p += (size_t)BH_CHUNK*96*9216*2;
  unsigned short* aP   = (unsigned short*)p; p += (size_t)BH_CHUNK*96*9216*2; // 28.31 MB
  unsigned short* wbf  = (unsigned short*)p; p += (size_t)4*1280*256*2;       //  2.62 MB
  float2*         part = (float2*)p;         p += 1024*8;
  float*          stats= (float*)p;          p += 256;
  float*          pool = (float*)p;          p += 128*256*4;

  k_gather<<<dim3(NPAIR), dim3(256), 0, stream>>>(adj, emb, x);
  k_wconv <<<dim3(1280),  dim3(256), 0, stream>>>(qkvw, wbf);
  for (int l = 0; l < 4; ++l){
    k_stats1<<<dim3(1024), dim3(256), 0, stream>>>(x, part);
    k_stats2<<<dim3(1),    dim3(256), 0, stream>>>(part, stats);
    k_norm  <<<dim3(9216), dim3(256), 0, stream>>>(x, stats, y);
    k_gemm  <<<dim3(10, 288), dim3(256), 0, stream>>>(y, wbf + (size_t)l*1280*256, qkv5);
    for (int c0 = 0; c0 < 32; c0 += BH_CHUNK){
      k_scores1<<<dim3(BH_CHUNK*96), dim3(256), 0, stream>>>(qkv5, s1, c0);
      k_attn2 <<<dim3(BH_CHUNK*96), dim3(256), 0, stream>>>(qkv5, s1, aP, x, c0);
      k_attn1 <<<dim3(BH_CHUNK*96), dim3(256), 0, stream>>>(aP, qkv5, x, c0);
    }
  }
  k_pool<<<dim3(128), dim3(256), 0, stream>>>(x, pool);
  k_head<<<dim3(4),   dim3(256), 0, stream>>>(pool, hw, hb, (float*)d_out);
}

// Round 5
// 872.062 us; speedup vs baseline: 2.5277x; 1.0159x over previous
//
#include <hip/hip_runtime.h>

// ---------------- problem constants ----------------
#define B_ 4
#define N_ 96
#define C_ 256
#define NPAIR (B_*N_*N_)        // 36864 pair rows
#define CE (NPAIR*C_)           // 9437184 elements per qkv slab
#define SCALE 8.838834764831844f  // 50/sqrt(32)
// ws budget: 256 MiB (fill kernels write 268.4 MB). Usage here ~248 MB.

typedef __attribute__((ext_vector_type(4))) float f32x4;
typedef __attribute__((ext_vector_type(8))) __bf16 bf16x8;
typedef __attribute__((ext_vector_type(4))) unsigned short u16x4;
typedef __attribute__((ext_vector_type(8))) unsigned short u16x8;

__device__ __forceinline__ unsigned short f2bf(float f){
  __bf16 h = (__bf16)f;                      // RNE convert
  return __builtin_bit_cast(unsigned short, h);
}

// async global->LDS, 16B per lane; lds dest = wave-uniform base + lane*16
__device__ __forceinline__ void gload16(const void* g, void* l){
  __builtin_amdgcn_global_load_lds((const __attribute__((address_space(1))) unsigned int*)g,
                                   (__attribute__((address_space(3))) unsigned int*)l,
                                   16, 0, 0);
}

// ---------------- K_init: zero stats partials (512 f) + pool acc (1024 f) ----------------
__global__ __launch_bounds__(256) void k_init(float* __restrict__ z){
  for (int i = threadIdx.x; i < 1536; i += 256) z[i] = 0.f;
}

// ---------------- K0: x = emb[adj] (fp32) + stats partials for layer-0 norm ----------------
// grid 2304, each block: 16 pairs x 256 ch
__global__ __launch_bounds__(256) void k_gather(const int* __restrict__ adj,
                                                const float* __restrict__ emb,
                                                float* __restrict__ x,
                                                float2* __restrict__ part){
  int tid = threadIdx.x;
  int lp = tid >> 4, lane16 = tid & 15;
  int pair = blockIdx.x*16 + lp;
  int row = adj[pair];
  const f32x4* src = (const f32x4*)(emb + (size_t)row*C_);
  f32x4*       dst = (f32x4*)(x + (size_t)pair*C_);
  float s = 0.f, q = 0.f;
  for (int v = 0; v < 4; ++v){
    f32x4 t = src[v*16 + lane16];
    dst[v*16 + lane16] = t;
    s += t.x + t.y + t.z + t.w;
    q += t.x*t.x + t.y*t.y + t.z*t.z + t.w*t.w;
  }
  __shared__ float rs[256], rq[256];
  rs[tid] = s; rq[tid] = q; __syncthreads();
  for (int o = 128; o > 0; o >>= 1){
    if (tid < o){ rs[tid] += rs[tid+o]; rq[tid] += rq[tid+o]; }
    __syncthreads();
  }
  if (tid == 0){
    float* pp = (float*)&part[blockIdx.x & 63];
    atomicAdd(pp, rs[0]); atomicAdd(pp+1, rq[0]);
  }
}

// ---------------- K0b: qkv weights fp32 -> bf16 (all 4 layers) ----------------
__global__ __launch_bounds__(256) void k_wconv(const float* __restrict__ w,
                                               unsigned short* __restrict__ wb){
  int i = blockIdx.x*256 + threadIdx.x;
  f32x4 v = ((const f32x4*)w)[i];
  u16x4 o;
  o.x = f2bf(v.x); o.y = f2bf(v.y); o.z = f2bf(v.z); o.w = f2bf(v.w);
  ((u16x4*)wb)[i] = o;
}

// ---------------- K3: finalize stats from 64 partials + y = bf16((x-mean)*rstd) ----------------
__global__ __launch_bounds__(256) void k_norm(const float* __restrict__ x,
                                              const float2* __restrict__ part,
                                              unsigned short* __restrict__ y){
  double S = 0.0, Q = 0.0;
  for (int i = 0; i < 64; ++i){ float2 pp = part[i]; S += (double)pp.x; Q += (double)pp.y; }
  float mean = (float)(S / (double)CE);
  float rstd = (float)(1.0 / sqrt((Q - S*S/(double)CE) / (double)(CE - 1)));
  int i = blockIdx.x*256 + threadIdx.x;    // 9216 blocks, one f32x4 each
  f32x4 v = ((const f32x4*)x)[i];
  u16x4 o;
  o.x = f2bf((v.x-mean)*rstd); o.y = f2bf((v.y-mean)*rstd);
  o.z = f2bf((v.z-mean)*rstd); o.w = f2bf((v.w-mean)*rstd);
  ((u16x4*)y)[i] = o;
}

// ---------------- K4: qkv GEMM, LDS-staged coalesced epilogue ----------------
// C[m,n] = sum_k Y[m,k]*W[n,k];  M=36864 N=1280 K=256. 128x128 tile, BK=64.
// Output: qkv5[slab][bh][i][j][d], slab in {q,k1,k2,v1,v2}, all natural layout.
__global__ __launch_bounds__(256) void k_gemm(const unsigned short* __restrict__ Y,
                                              const unsigned short* __restrict__ W,
                                              unsigned short* __restrict__ qkv5){
  __shared__ unsigned short smem[128*128];   // 32 KB: As | Bs during K-loop, C-stage in epilogue
  unsigned short* As = smem;
  unsigned short* Bs = smem + 128*64;
  const int tid = threadIdx.x;
  const int w = tid >> 6, lane = tid & 63;
  const int quad = lane >> 4, l16 = lane & 15;
  const int m0 = blockIdx.y * 128, n0 = blockIdx.x * 128;
  const int mw = (w & 1) * 64, nw = (w >> 1) * 64;
  f32x4 acc[4][4] = {};

  for (int kt = 0; kt < 256; kt += 64){
    // stage A,B tiles: LDS slot s of row r holds global 16B chunk s^(r&7)
    const int rbase = w * 32;
    const int rowoff = lane >> 3;           // 0..7 (== row&7)
    const int kg = (lane & 7) ^ rowoff;     // global chunk for lds slot
    for (int i8 = 0; i8 < 4; ++i8){
      int row = rbase + i8*8 + rowoff;
      gload16(Y + (size_t)(m0+row)*256 + kt + kg*8, &As[(rbase + i8*8)*64]);
      gload16(W + (size_t)(n0+row)*256 + kt + kg*8, &Bs[(rbase + i8*8)*64]);
    }
    __syncthreads();
    for (int ks = 0; ks < 2; ++ks){
      bf16x8 af[4], bf[4];
      for (int t4 = 0; t4 < 4; ++t4){
        int rm = mw + t4*16 + l16;
        af[t4] = *(const bf16x8*)((const char*)As + rm*128 + ((((ks<<2)|quad) ^ (rm&7))*16));
        int rn = nw + t4*16 + l16;
        bf[t4] = *(const bf16x8*)((const char*)Bs + rn*128 + ((((ks<<2)|quad) ^ (rn&7))*16));
      }
      for (int mi = 0; mi < 4; ++mi)
        for (int ni = 0; ni < 4; ++ni)
          acc[mi][ni] = __builtin_amdgcn_mfma_f32_16x16x32_bf16(af[mi], bf[ni], acc[mi][ni], 0, 0, 0);
    }
    __syncthreads();
  }

  // ---- epilogue: stage C tile (bf16) in LDS, then coalesced vector stores ----
  for (int mi = 0; mi < 4; ++mi)
    for (int ni = 0; ni < 4; ++ni)
      for (int r = 0; r < 4; ++r){
        int row = mw + mi*16 + quad*4 + r;
        int col = nw + ni*16 + l16;
        smem[row*128 + col] = f2bf(acc[mi][ni][r]);
      }
  __syncthreads();

  const int t_slab = n0 >> 8;               // n-tile lies fully within one slab
  const int hbase  = (n0 >> 5) & 7;
  unsigned short* slab = qkv5 + (size_t)t_slab*CE;
  const int trow = tid >> 4;                // 0..15
  const int tcol = (tid & 15) * 8;          // 0..120
  const int h  = hbase + (tcol >> 5);
  const int dd = tcol & 31;
  for (int pass = 0; pass < 8; ++pass){
    int row = pass*16 + trow;
    int gm = m0 + row;
    int b = gm / 9216; int rem = gm - b*9216;
    int ii = rem / 96, jj = rem - (rem/96)*96;
    u16x8 vv = *(const u16x8*)&smem[row*128 + tcol];
    *(u16x8*)&slab[(((size_t)(b*8+h)*96 + ii)*96 + jj)*32 + dd] = vv;
  }
}

// ---------------- K5: branch-1 scores; block = bh*96 + i ----------------
// s1[bh,i,j,p] = scale * (q[i,j,:] . k1[i,p,:])  (fp16)
__global__ __launch_bounds__(256) void k_scores1(const unsigned short* __restrict__ qkv5,
                                                 _Float16* __restrict__ s1){
  __shared__ unsigned short Qs[96*40], Ks[96*40];
  int wg = blockIdx.x;                       // bh*96 + i
  int tid = threadIdx.x;
  size_t gslab = (size_t)wg*3072;
  const unsigned short* qp = qkv5 + 0*(size_t)CE + gslab;   // q  [bh][i][j][d]
  const unsigned short* kp = qkv5 + 1*(size_t)CE + gslab;   // k1 [bh][i][p][d]
  for (int g = tid; g < 768; g += 256){
    int j = g >> 3, q4 = g & 7;
    *(u16x4*)&Qs[j*40 + q4*4] = *(const u16x4*)&qp[j*32 + q4*4];
    *(u16x4*)&Ks[j*40 + q4*4] = *(const u16x4*)&kp[j*32 + q4*4];
  }
  __syncthreads();
  int w = tid >> 6, lane = tid & 63, quad = lane >> 4, l16 = lane & 15;
  _Float16* sp = s1 + (size_t)wg*9216;
  for (int r = 0; r < 9; ++r){
    int tile = w*9 + r; int jt = tile/6, pt = tile - jt*6;
    bf16x8 a = *(const bf16x8*)((const char*)Qs + (jt*16 + l16)*80 + quad*16);
    bf16x8 b = *(const bf16x8*)((const char*)Ks + (pt*16 + l16)*80 + quad*16);
    f32x4 c = {0.f,0.f,0.f,0.f};
    c = __builtin_amdgcn_mfma_f32_16x16x32_bf16(a, b, c, 0, 0, 0);
    int col = pt*16 + l16;
    for (int rr = 0; rr < 4; ++rr){
      int row = jt*16 + quad*4 + rr;
      sp[row*96 + col] = (_Float16)(c[rr] * SCALE);
    }
  }
}

// ---------------- K6: branch-2 scores + softmax + O2, per (bh, j) ----------------
__global__ __launch_bounds__(256) void k_attn2(const unsigned short* __restrict__ qkv5,
                                               const _Float16* __restrict__ s1,
                                               unsigned short* __restrict__ a_out,
                                               float* __restrict__ x){
  __shared__ unsigned short Qs[96*40], Ks[96*40], Vd[32*112];
  __shared__ float Sf[96*100];
  int wg = blockIdx.x; int bh = wg/96, jj = wg - bh*96;
  int b = bh >> 3, h = bh & 7;
  int tid = threadIdx.x;
  const unsigned short* qn  = qkv5 + 0*(size_t)CE;
  const unsigned short* k2n = qkv5 + 2*(size_t)CE;
  const unsigned short* v2n = qkv5 + 4*(size_t)CE;
  for (int g = tid; g < 768; g += 256){
    int p = g >> 3, q4 = g & 7;                 // p = row (i or pivot), q4*4 = d0
    size_t base = (((size_t)bh*96 + p)*96 + jj)*32 + q4*4;
    *(u16x4*)&Qs[p*40 + q4*4] = *(const u16x4*)&qn[base];
    *(u16x4*)&Ks[p*40 + q4*4] = *(const u16x4*)&k2n[base];
    u16x4 v = *(const u16x4*)&v2n[base];
    int d0 = q4*4;
    Vd[(d0+0)*112 + p] = v.x; Vd[(d0+1)*112 + p] = v.y;
    Vd[(d0+2)*112 + p] = v.z; Vd[(d0+3)*112 + p] = v.w;
  }
  __syncthreads();
  int w = tid >> 6, lane = tid & 63, quad = lane >> 4, l16 = lane & 15;
  // S2 tiles + add s1
  for (int r = 0; r < 9; ++r){
    int tile = w*9 + r; int it = tile/6, pt = tile - it*6;
    bf16x8 a = *(const bf16x8*)((const char*)Qs + (it*16 + l16)*80 + quad*16);
    bf16x8 bb = *(const bf16x8*)((const char*)Ks + (pt*16 + l16)*80 + quad*16);
    f32x4 c = {0.f,0.f,0.f,0.f};
    c = __builtin_amdgcn_mfma_f32_16x16x32_bf16(a, bb, c, 0, 0, 0);
    int col = pt*16 + l16;
    for (int rr = 0; rr < 4; ++rr){
      int row = it*16 + quad*4 + rr;   // i
      float v = c[rr]*SCALE + (float)s1[(((size_t)bh*96 + row)*96 + jj)*96 + col];
      Sf[row*100 + col] = v;
    }
  }
  __syncthreads();
  // softmax over p per row i (vectorized f32x4: row pitch 400B, 16B-aligned)
  if (tid < 96){
    f32x4* rp = (f32x4*)&Sf[tid*100];
    f32x4 m4 = rp[0];
    for (int p = 1; p < 24; ++p){
      f32x4 v = rp[p];
      m4.x = fmaxf(m4.x, v.x); m4.y = fmaxf(m4.y, v.y);
      m4.z = fmaxf(m4.z, v.z); m4.w = fmaxf(m4.w, v.w);
    }
    float m = fmaxf(fmaxf(m4.x, m4.y), fmaxf(m4.z, m4.w));
    f32x4 s4 = {0.f,0.f,0.f,0.f};
    for (int p = 0; p < 24; ++p){
      f32x4 v = rp[p], e;
      e.x = __expf(v.x - m); e.y = __expf(v.y - m);
      e.z = __expf(v.z - m); e.w = __expf(v.w - m);
      rp[p] = e; s4 += e;
    }
    float inv = 1.f / (s4.x + s4.y + s4.z + s4.w);
    for (int p = 0; p < 24; ++p) rp[p] *= inv;
  }
  __syncthreads();
  // write probs (layout [bh, j, i, p]), vectorized
  unsigned short* ap = a_out + (size_t)wg*9216;
  for (int g = tid; g < 2304; g += 256){
    int i = g / 24, pq = (g - i*24)*4;
    f32x4 v = *(const f32x4*)&Sf[i*100 + pq];
    u16x4 o;
    o.x = f2bf(v.x); o.y = f2bf(v.y); o.z = f2bf(v.z); o.w = f2bf(v.w);
    *(u16x4*)&ap[i*96 + pq] = o;
  }
  // O2 = A(96i x 96p) @ V2(96p x 32d) -> store x[b,i,jj,h*32+d]
  for (int r = 0; r < 3; ++r){
    int tile = w*3 + r; int it = tile >> 1, dt = tile & 1;
    f32x4 c = {0.f,0.f,0.f,0.f};
    for (int kp3 = 0; kp3 < 3; ++kp3){
      int row = it*16 + l16;
      const float* sp = &Sf[row*100 + kp3*32 + quad*8];
      bf16x8 a;
      for (int t = 0; t < 8; ++t) a[t] = (__bf16)sp[t];
      bf16x8 bb = *(const bf16x8*)((const char*)Vd + (dt*16 + l16)*224 + kp3*64 + quad*16);
      c = __builtin_amdgcn_mfma_f32_16x16x32_bf16(a, bb, c, 0, 0, 0);
    }
    int d = dt*16 + l16;
    for (int rr = 0; rr < 4; ++rr){
      int i = it*16 + quad*4 + rr;
      x[(((size_t)b*96 + i)*96 + jj)*256 + h*32 + d] = c[rr];
    }
  }
}

// ---------------- K7: O1 per (bh, i): x += A @ V1; fused stats OR pool ----------------
__global__ __launch_bounds__(256) void k_attn1(const unsigned short* __restrict__ a_in,
                                               const unsigned short* __restrict__ qkv5,
                                               float* __restrict__ x,
                                               float2* __restrict__ statsPart,
                                               float* __restrict__ poolAcc,
                                               int last){
  __shared__ unsigned short As[96*112], Vd[32*112];
  __shared__ float redS[256], redQ[256];
  __shared__ float poolL[32];
  int wg = blockIdx.x; int bh = wg/96, ii = wg - bh*96;
  int b = bh >> 3, h = bh & 7;
  int tid = threadIdx.x;
  if (tid < 32) poolL[tid] = 0.f;
  const unsigned short* vp = qkv5 + 3*(size_t)CE + ((size_t)bh*96 + ii)*3072;  // v1 [bh][i][p][d]
  for (int g = tid; g < 768; g += 256){
    int p = g >> 3, q4 = g & 7;
    u16x4 v = *(const u16x4*)&vp[p*32 + q4*4];
    int d0 = q4*4;
    Vd[(d0+0)*112 + p] = v.x; Vd[(d0+1)*112 + p] = v.y;
    Vd[(d0+2)*112 + p] = v.z; Vd[(d0+3)*112 + p] = v.w;
  }
  for (int g = tid; g < 1152; g += 256){     // 96 j rows x 12 u16x8
    int j = g / 12, q8 = g - j*12;
    *(u16x8*)&As[j*112 + q8*8] =
      *(const u16x8*)&a_in[((size_t)(bh*96 + j))*9216 + ii*96 + q8*8];
  }
  __syncthreads();
  int w = tid >> 6, lane = tid & 63, quad = lane >> 4, l16 = lane & 15;
  float ls = 0.f, lq = 0.f;
  for (int r = 0; r < 3; ++r){
    int tile = w*3 + r; int jt = tile >> 1, dt = tile & 1;
    f32x4 c = {0.f,0.f,0.f,0.f};
    for (int kp3 = 0; kp3 < 3; ++kp3){
      bf16x8 a = *(const bf16x8*)((const char*)As + (jt*16 + l16)*224 + kp3*64 + quad*16);
      bf16x8 bb = *(const bf16x8*)((const char*)Vd + (dt*16 + l16)*224 + kp3*64 + quad*16);
      c = __builtin_amdgcn_mfma_f32_16x16x32_bf16(a, bb, c, 0, 0, 0);
    }
    int d = dt*16 + l16;
    float dsum = 0.f;
    for (int rr = 0; rr < 4; ++rr){
      int j = jt*16 + quad*4 + rr;
      size_t xi = (((size_t)b*96 + ii)*96 + j)*256 + h*32 + d;
      float val = x[xi] + c[rr];
      if (!last){ x[xi] = val; ls += val; lq += val*val; }
      else dsum += val;
    }
    if (last) atomicAdd(&poolL[d], dsum);
  }
  if (!last){
    redS[tid] = ls; redQ[tid] = lq; __syncthreads();
    for (int o = 128; o > 0; o >>= 1){
      if (tid < o){ redS[tid] += redS[tid+o]; redQ[tid] += redQ[tid+o]; }
      __syncthreads();
    }
    if (tid == 0){
      float* pp = (float*)&statsPart[blockIdx.x & 63];
      atomicAdd(pp, redS[0]); atomicAdd(pp+1, redQ[0]);
    }
  } else {
    __syncthreads();
    if (tid < 32) atomicAdd(&poolAcc[b*256 + h*32 + tid], poolL[tid]);
  }
}

// ---------------- K9: head (fp32 weights, fp32 out) ----------------
__global__ __launch_bounds__(256) void k_head(const float* __restrict__ poolAcc,
                                              const float* __restrict__ hw,
                                              const float* __restrict__ hb,
                                              float* __restrict__ out){
  int b = blockIdx.x, t = threadIdx.x;
  __shared__ float xm[256];
  xm[t] = poolAcc[b*256 + t] * (1.0f/9216.0f);
  __syncthreads();
  float o = hb[t];
  for (int c = 0; c < 256; ++c) o += xm[c] * hw[t*256 + c];
  out[b*256 + t] = o;
}

// ---------------- launch ----------------
extern "C" void kernel_launch(void* const* d_in, const int* in_sizes, int n_in,
                              void* d_out, int out_size, void* d_ws, size_t ws_size,
                              hipStream_t stream){
  (void)in_sizes; (void)n_in; (void)out_size; (void)ws_size;
  const int*   adj  = (const int*)d_in[0];
  const float* emb  = (const float*)d_in[1];
  const float* qkvw = (const float*)d_in[2];
  const float* hw   = (const float*)d_in[3];
  const float* hb   = (const float*)d_in[4];

  // workspace layout (~248 MB total; ws is 256 MiB)
  char* p = (char*)d_ws;
  float*          x    = (float*)p;          p += (size_t)CE*4;            //  37.75 MB
  unsigned short* qkv5 = (unsigned short*)p; p += (size_t)5*CE*2;          //  94.37 MB
  // region R1: y (bf16, 18.87 MB) aliased under s1 (fp16, 56.62 MB); y dead before scores1 runs
  unsigned short* y    = (unsigned short*)p;
  _Float16*       s1   = (_Float16*)p;       p += (size_t)32*96*9216*2;    //  56.62 MB
  unsigned short* aP   = (unsigned short*)p; p += (size_t)32*96*9216*2;    //  56.62 MB
  unsigned short* wbf  = (unsigned short*)p; p += (size_t)4*1280*256*2;    //   2.62 MB
  float2*         part = (float2*)p;         p += 4*64*sizeof(float2);     // stats partials [4][64]
  float*          pool = (float*)p;          p += 1024*sizeof(float);      // contiguous after part

  k_init  <<<dim3(1),     dim3(256), 0, stream>>>((float*)part);
  k_gather<<<dim3(2304),  dim3(256), 0, stream>>>(adj, emb, x, part);
  k_wconv <<<dim3(1280),  dim3(256), 0, stream>>>(qkvw, wbf);
  for (int l = 0; l < 4; ++l){
    k_norm   <<<dim3(9216),    dim3(256), 0, stream>>>(x, part + l*64, y);
    k_gemm   <<<dim3(10, 288), dim3(256), 0, stream>>>(y, wbf + (size_t)l*1280*256, qkv5);
    k_scores1<<<dim3(3072),    dim3(256), 0, stream>>>(qkv5, s1);
    k_attn2  <<<dim3(3072),    dim3(256), 0, stream>>>(qkv5, s1, aP, x);
    k_attn1  <<<dim3(3072),    dim3(256), 0, stream>>>(aP, qkv5, x,
                                                       part + (l+1 < 4 ? (l+1)*64 : 0),
                                                       pool, (l == 3) ? 1 : 0);
  }
  k_head<<<dim3(4), dim3(256), 0, stream>>>(pool, hw, hb, (float*)d_out);
}